// Round 1
// baseline (428.690 us; speedup 1.0000x reference)
//
#include <hip/hip_runtime.h>

// 3x3 high-pass: k = 1/8 everywhere, -1 at center, SAME (zero) padding,
// then |y| + 1e-5.  y = (sum9)/8 - (9/8)*center.
//
// Input x: (8, 32, 512, 512) f32 -> 256 planes of 512x512.
// Memory-bound; rolling 3-row register window, float4-vectorized.

#define HH 512
#define WW 512
#define RPT 16   // output rows per thread

__global__ __launch_bounds__(256) void highpass3x3_kernel(
    const float* __restrict__ x, float* __restrict__ out)
{
    const int plane = blockIdx.y;
    const int w0 = (int)threadIdx.x * 4;                       // 128 threads * 4 = 512 cols
    const int h0 = ((int)blockIdx.x * 2 + (int)threadIdx.y) * RPT;

    const float* __restrict__ xp = x + (size_t)plane * (HH * WW);
    float* __restrict__ op = out + (size_t)plane * (HH * WW);

    const bool has_l = (w0 > 0);
    const bool has_r = (w0 + 4 < WW);

    float4 hsA, hsB, hsC;   // horizontal 3-sums for rows h-1, h, h+1
    float4 cB, cC;          // center float4 for rows h, h+1

    // ---- prologue: row h0-1 (may be zero padding) ----
    {
        const int h = h0 - 1;
        float4 c; float l, r;
        if (h >= 0) {
            const float* row = xp + h * WW + w0;
            c = *reinterpret_cast<const float4*>(row);
            l = has_l ? row[-1] : 0.0f;
            r = has_r ? row[4]  : 0.0f;
        } else {
            c = make_float4(0.f, 0.f, 0.f, 0.f); l = 0.f; r = 0.f;
        }
        hsA.x = l   + c.x + c.y;
        hsA.y = c.x + c.y + c.z;
        hsA.z = c.y + c.z + c.w;
        hsA.w = c.z + c.w + r;
    }
    // ---- prologue: row h0 ----
    {
        const float* row = xp + h0 * WW + w0;
        float4 c = *reinterpret_cast<const float4*>(row);
        float l = has_l ? row[-1] : 0.0f;
        float r = has_r ? row[4]  : 0.0f;
        hsB.x = l   + c.x + c.y;
        hsB.y = c.x + c.y + c.z;
        hsB.z = c.y + c.z + c.w;
        hsB.w = c.z + c.w + r;
        cB = c;
    }

    #pragma unroll
    for (int i = 0; i < RPT; ++i) {
        const int h  = h0 + i;
        const int hn = h + 1;
        // load row h+1
        {
            float4 c; float l, r;
            if (hn < HH) {
                const float* row = xp + hn * WW + w0;
                c = *reinterpret_cast<const float4*>(row);
                l = has_l ? row[-1] : 0.0f;
                r = has_r ? row[4]  : 0.0f;
            } else {
                c = make_float4(0.f, 0.f, 0.f, 0.f); l = 0.f; r = 0.f;
            }
            hsC.x = l   + c.x + c.y;
            hsC.y = c.x + c.y + c.z;
            hsC.z = c.y + c.z + c.w;
            hsC.w = c.z + c.w + r;
            cC = c;
        }

        float4 y;
        y.x = fabsf((hsA.x + hsB.x + hsC.x) * 0.125f - 1.125f * cB.x) + 1e-5f;
        y.y = fabsf((hsA.y + hsB.y + hsC.y) * 0.125f - 1.125f * cB.y) + 1e-5f;
        y.z = fabsf((hsA.z + hsB.z + hsC.z) * 0.125f - 1.125f * cB.z) + 1e-5f;
        y.w = fabsf((hsA.w + hsB.w + hsC.w) * 0.125f - 1.125f * cB.w) + 1e-5f;

        *reinterpret_cast<float4*>(op + h * WW + w0) = y;

        hsA = hsB; hsB = hsC; cB = cC;
    }
}

extern "C" void kernel_launch(void* const* d_in, const int* in_sizes, int n_in,
                              void* d_out, int out_size, void* d_ws, size_t ws_size,
                              hipStream_t stream) {
    const float* x = (const float*)d_in[0];
    float* out = (float*)d_out;

    const int planes = in_sizes[0] / (HH * WW);   // 8*32 = 256

    dim3 block(128, 2, 1);                         // 256 threads; full 512-wide row
    dim3 grid(HH / (2 * RPT), planes, 1);          // (16, 256)

    highpass3x3_kernel<<<grid, block, 0, stream>>>(x, out);
}